// Round 1
// baseline (547.038 us; speedup 1.0000x reference)
//
#include <hip/hip_runtime.h>
#include <hip/hip_bf16.h>

#define B_ 4
#define T_ 2048
#define C_ 1024
#define H_ 16
#define HD_ 64
#define M_ (B_*T_)   // 8192

typedef __attribute__((ext_vector_type(8))) short short8;
typedef __attribute__((ext_vector_type(4))) float f32x4;
typedef unsigned short u16;

__device__ __forceinline__ u16 f2bf(float f){
  unsigned int x = __builtin_bit_cast(unsigned int, f);
  x += 0x7fffu + ((x >> 16) & 1u);   // RNE
  return (u16)(x >> 16);
}

// ---------------- fp32 -> bf16 convert ----------------
__global__ __launch_bounds__(256) void cvt_kernel(const float* __restrict__ in,
                                                  u16* __restrict__ out, int n4){
  int i = blockIdx.x * 256 + threadIdx.x;
  if (i >= n4) return;
  float4 f = reinterpret_cast<const float4*>(in)[i];
  ushort4 u;
  u.x = f2bf(f.x); u.y = f2bf(f.y); u.z = f2bf(f.z); u.w = f2bf(f.w);
  reinterpret_cast<ushort4*>(out)[i] = u;
}

// ---------------- GEMM: C[M,N] = A[M,K] * Bt[N,K]^T + bias ----------------
// MODE 0: scatter-epilogue into q/k/v [B,H,T,HD] bf16.  MODE 1: fp32 row-major out.
template<int MODE>
__global__ __launch_bounds__(256)
void gemm_bt(const u16* __restrict__ A, const u16* __restrict__ Bt,
             const float* __restrict__ bias, float* __restrict__ Cf,
             u16* __restrict__ Qo, u16* __restrict__ Ko, u16* __restrict__ Vo,
             int N, int K)
{
  __shared__ u16 As[128][72];   // 72*2 = 144 B pitch = 9*16B: aligned b128, conflict-free
  __shared__ u16 Bs[128][72];
  const int tid = threadIdx.x;
  const int wave = tid >> 6, lane = tid & 63;
  const int lo = lane & 15, hi = lane >> 4;
  const int wm = (wave >> 1) * 64, wn = (wave & 1) * 64;
  const long bm = (long)blockIdx.y * 128, bn = (long)blockIdx.x * 128;

  f32x4 acc[4][4];
  #pragma unroll
  for (int i = 0; i < 4; i++)
    #pragma unroll
    for (int j = 0; j < 4; j++)
      acc[i][j] = (f32x4){0.f, 0.f, 0.f, 0.f};

  const int r = tid >> 3;            // 0..31
  const int ccol = (tid & 7) * 8;    // 0..56

  for (int k0 = 0; k0 < K; k0 += 64){
    if (k0) __syncthreads();
    #pragma unroll
    for (int rr = 0; rr < 4; rr++){
      int row = r + rr * 32;
      *reinterpret_cast<short8*>(&As[row][ccol]) =
        *reinterpret_cast<const short8*>(&A[(bm + row) * K + k0 + ccol]);
      *reinterpret_cast<short8*>(&Bs[row][ccol]) =
        *reinterpret_cast<const short8*>(&Bt[(bn + row) * K + k0 + ccol]);
    }
    __syncthreads();
    #pragma unroll
    for (int kk = 0; kk < 64; kk += 32){
      short8 af[4], bf[4];
      #pragma unroll
      for (int mi = 0; mi < 4; mi++)
        af[mi] = *reinterpret_cast<const short8*>(&As[wm + mi*16 + lo][kk + hi*8]);
      #pragma unroll
      for (int ni = 0; ni < 4; ni++)
        bf[ni] = *reinterpret_cast<const short8*>(&Bs[wn + ni*16 + lo][kk + hi*8]);
      #pragma unroll
      for (int mi = 0; mi < 4; mi++)
        #pragma unroll
        for (int ni = 0; ni < 4; ni++)
          acc[mi][ni] = __builtin_amdgcn_mfma_f32_16x16x32_bf16(af[mi], bf[ni], acc[mi][ni], 0, 0, 0);
    }
  }

  #pragma unroll
  for (int mi = 0; mi < 4; mi++){
    #pragma unroll
    for (int ni = 0; ni < 4; ni++){
      #pragma unroll
      for (int rg = 0; rg < 4; rg++){
        long rowg = bm + wm + mi*16 + hi*4 + rg;
        long colg = bn + wn + ni*16 + lo;
        float v = acc[mi][ni][rg] + bias[colg];
        if (MODE == 0){
          int part = (int)(colg >> 10), cc = (int)(colg & 1023);
          int h = cc >> 6, d = cc & 63;
          long b = rowg >> 11, t = rowg & 2047;
          u16* dst = (part == 0) ? Qo : ((part == 1) ? Ko : Vo);
          dst[(((b << 4) + h) * 2048 + t) * 64 + d] = f2bf(v);
        } else {
          Cf[rowg * (long)N + colg] = v;
        }
      }
    }
  }
}

// ---------------- causal flash attention, bf16 MFMA ----------------
// Q,K,V: [BH=64][T=2048][64] bf16.  Y: [B,T,C] bf16 (head-merged).
__global__ __launch_bounds__(256)
void attn_kernel(const u16* __restrict__ Q, const u16* __restrict__ K,
                 const u16* __restrict__ V, u16* __restrict__ Y)
{
  __shared__ u16 Vt[64][40];       // V transposed [d][kv], pitch 80 B = 5*16B
  __shared__ u16 Ps[4][16][40];    // per-wave P [q][kv]
  const int bh = blockIdx.y;
  const int q0 = blockIdx.x * 64;
  const int tid = threadIdx.x, wave = tid >> 6, lane = tid & 63;
  const int lo = lane & 15, hi = lane >> 4;
  const u16* Qb = Q + (size_t)bh * T_ * 64;
  const u16* Kb = K + (size_t)bh * T_ * 64;
  const u16* Vb = V + (size_t)bh * T_ * 64;

  // Q fragments for this wave's 16 rows (A-frag: row=lo, k(d)=kk*32+hi*8+j)
  const int qrow_f = q0 + wave * 16 + lo;
  short8 qf[2];
  qf[0] = *reinterpret_cast<const short8*>(&Qb[(size_t)qrow_f * 64 + hi * 8]);
  qf[1] = *reinterpret_cast<const short8*>(&Qb[(size_t)qrow_f * 64 + 32 + hi * 8]);

  f32x4 o[4];
  float m[4], lsum[4];
  #pragma unroll
  for (int i = 0; i < 4; i++){ o[i] = (f32x4){0.f,0.f,0.f,0.f}; m[i] = -1e30f; lsum[i] = 0.f; }

  const int svkv = tid >> 3;        // 0..31
  const int svd  = (tid & 7) * 8;   // 0..56
  const int ntiles = (q0 + 64) / 32;

  for (int jt = 0; jt < ntiles; jt++){
    const int k0 = jt * 32;
    if (jt) __syncthreads();
    { // stage V transposed
      short8 vv = *reinterpret_cast<const short8*>(&Vb[(size_t)(k0 + svkv) * 64 + svd]);
      #pragma unroll
      for (int j = 0; j < 8; j++) Vt[svd + j][svkv] = (u16)vv[j];
    }
    __syncthreads();

    // S = Q K^T (K frags direct from global; B-frag: col=kv=lo, k(d)=hi*8+j)
    f32x4 s[2] = {(f32x4){0.f,0.f,0.f,0.f}, (f32x4){0.f,0.f,0.f,0.f}};
    #pragma unroll
    for (int n = 0; n < 2; n++){
      const int krow = k0 + n * 16 + lo;
      short8 kf0 = *reinterpret_cast<const short8*>(&Kb[(size_t)krow * 64 + hi * 8]);
      short8 kf1 = *reinterpret_cast<const short8*>(&Kb[(size_t)krow * 64 + 32 + hi * 8]);
      s[n] = __builtin_amdgcn_mfma_f32_16x16x32_bf16(qf[0], kf0, s[n], 0, 0, 0);
      s[n] = __builtin_amdgcn_mfma_f32_16x16x32_bf16(qf[1], kf1, s[n], 0, 0, 0);
    }
    // scale + causal mask (C-layout: row q = hi*4+rg, col kv = n*16+lo)
    #pragma unroll
    for (int n = 0; n < 2; n++)
      #pragma unroll
      for (int rg = 0; rg < 4; rg++){
        int qq = q0 + wave * 16 + hi * 4 + rg;
        int kv = k0 + n * 16 + lo;
        float x = s[n][rg] * 0.125f;
        s[n][rg] = (kv <= qq) ? x : -1e30f;
      }
    // online softmax: row-reduce across the 16 lanes holding this row
    float alpha[4];
    #pragma unroll
    for (int rg = 0; rg < 4; rg++){
      float rm = fmaxf(s[0][rg], s[1][rg]);
      rm = fmaxf(rm, __shfl_xor(rm, 1));
      rm = fmaxf(rm, __shfl_xor(rm, 2));
      rm = fmaxf(rm, __shfl_xor(rm, 4));
      rm = fmaxf(rm, __shfl_xor(rm, 8));
      float mn = fmaxf(m[rg], rm);
      float p0 = __expf(s[0][rg] - mn);
      float p1 = __expf(s[1][rg] - mn);
      s[0][rg] = p0; s[1][rg] = p1;
      float rs = p0 + p1;
      rs += __shfl_xor(rs, 1);
      rs += __shfl_xor(rs, 2);
      rs += __shfl_xor(rs, 4);
      rs += __shfl_xor(rs, 8);
      alpha[rg] = __expf(m[rg] - mn);
      lsum[rg] = lsum[rg] * alpha[rg] + rs;
      m[rg] = mn;
    }
    #pragma unroll
    for (int n = 0; n < 4; n++)
      #pragma unroll
      for (int rg = 0; rg < 4; rg++)
        o[n][rg] *= alpha[rg];
    // P -> LDS (re-fragment for PV)
    #pragma unroll
    for (int n = 0; n < 2; n++)
      #pragma unroll
      for (int rg = 0; rg < 4; rg++)
        Ps[wave][hi * 4 + rg][n * 16 + lo] = f2bf(s[n][rg]);
    __syncthreads();
    // PV: A-frag P (row q = lo, k(kv) = hi*8+j), B-frag V^T (col d = lo, k = hi*8+j)
    short8 pf = *reinterpret_cast<const short8*>(&Ps[wave][lo][hi * 8]);
    #pragma unroll
    for (int n = 0; n < 4; n++){
      short8 vf = *reinterpret_cast<const short8*>(&Vt[n * 16 + lo][hi * 8]);
      o[n] = __builtin_amdgcn_mfma_f32_16x16x32_bf16(pf, vf, o[n], 0, 0, 0);
    }
  }

  // epilogue: y[b][t][h*64+d]
  const int b = bh >> 4, h = bh & 15;
  #pragma unroll
  for (int n = 0; n < 4; n++)
    #pragma unroll
    for (int rg = 0; rg < 4; rg++){
      int qq = q0 + wave * 16 + hi * 4 + rg;
      float val = o[n][rg] / lsum[rg];
      Y[((size_t)(b * 2048 + qq)) * 1024 + h * 64 + n * 16 + lo] = f2bf(val);
    }
}

// ---------------- launch ----------------
extern "C" void kernel_launch(void* const* d_in, const int* in_sizes, int n_in,
                              void* d_out, int out_size, void* d_ws, size_t ws_size,
                              hipStream_t stream)
{
  const float* x      = (const float*)d_in[0];
  const float* w_qkv  = (const float*)d_in[1];
  const float* b_qkv  = (const float*)d_in[2];
  const float* w_proj = (const float*)d_in[3];
  const float* b_proj = (const float*)d_in[4];
  float* out = (float*)d_out;

  char* ws = (char*)d_ws;
  u16* xb     = (u16*)(ws);                       // 16 MB  [8192,1024]
  u16* wqkvb  = (u16*)(ws + (16u << 20));         //  6 MB  [3072,1024]
  u16* wprojb = (u16*)(ws + (22u << 20));         //  2 MB  [1024,1024]
  u16* qb     = (u16*)(ws + (24u << 20));         // 16 MB  [64,2048,64]
  u16* kb     = (u16*)(ws + (40u << 20));         // 16 MB
  u16* vb     = (u16*)(ws + (56u << 20));         // 16 MB
  u16* yb     = (u16*)(ws + (72u << 20));         // 16 MB  [8192,1024]

  int nx = B_ * T_ * C_ / 4;          // 2097152
  int nw1 = 3 * C_ * C_ / 4;          //  786432
  int nw2 = C_ * C_ / 4;              //  262144
  cvt_kernel<<<(nx  + 255) / 256, 256, 0, stream>>>(x,      xb,     nx);
  cvt_kernel<<<(nw1 + 255) / 256, 256, 0, stream>>>(w_qkv,  wqkvb,  nw1);
  cvt_kernel<<<(nw2 + 255) / 256, 256, 0, stream>>>(w_proj, wprojb, nw2);

  dim3 g1(3072 / 128, M_ / 128);
  gemm_bt<0><<<g1, 256, 0, stream>>>(xb, wqkvb, b_qkv, nullptr, qb, kb, vb, 3072, C_);

  dim3 ga(T_ / 64, B_ * H_);
  attn_kernel<<<ga, 256, 0, stream>>>(qb, kb, vb, yb);

  dim3 g2(1024 / 128, M_ / 128);
  gemm_bt<1><<<g2, 256, 0, stream>>>(yb, wprojb, b_proj, out, nullptr, nullptr, nullptr, C_, C_);
}

// Round 2
// 384.545 us; speedup vs baseline: 1.4226x; 1.4226x over previous
//
#include <hip/hip_runtime.h>
#include <hip/hip_bf16.h>

#define B_ 4
#define T_ 2048
#define C_ 1024
#define H_ 16
#define HD_ 64
#define M_ (B_*T_)   // 8192

typedef __attribute__((ext_vector_type(8))) short short8;
typedef __attribute__((ext_vector_type(4))) float f32x4;
typedef unsigned short u16;

__device__ __forceinline__ u16 f2bf(float f){
  unsigned int x = __builtin_bit_cast(unsigned int, f);
  x += 0x7fffu + ((x >> 16) & 1u);   // RNE
  return (u16)(x >> 16);
}

// ---------------- fp32 -> bf16 convert ----------------
__global__ __launch_bounds__(256) void cvt_kernel(const float* __restrict__ in,
                                                  u16* __restrict__ out, int n4){
  int i = blockIdx.x * 256 + threadIdx.x;
  if (i >= n4) return;
  float4 f = reinterpret_cast<const float4*>(in)[i];
  ushort4 u;
  u.x = f2bf(f.x); u.y = f2bf(f.y); u.z = f2bf(f.z); u.w = f2bf(f.w);
  reinterpret_cast<ushort4*>(out)[i] = u;
}

// ---------------- GEMM: C[M,N] = A[M,K] * Bt[N,K]^T + bias ----------------
// MODE 0: scatter-epilogue into q/k/v [B,H,T,HD] bf16 (Q pre-scaled by 0.125).
// MODE 1: fp32 row-major out.
template<int MODE>
__global__ __launch_bounds__(256)
void gemm_bt(const u16* __restrict__ A, const u16* __restrict__ Bt,
             const float* __restrict__ bias, float* __restrict__ Cf,
             u16* __restrict__ Qo, u16* __restrict__ Ko, u16* __restrict__ Vo,
             int N, int K)
{
  __shared__ u16 As[128][72];   // 144 B pitch = 9*16B: aligned b128, conflict-free
  __shared__ u16 Bs[128][72];
  const int tid = threadIdx.x;
  const int wave = tid >> 6, lane = tid & 63;
  const int lo = lane & 15, hi = lane >> 4;
  const int wm = (wave >> 1) * 64, wn = (wave & 1) * 64;
  const long bm = (long)blockIdx.y * 128, bn = (long)blockIdx.x * 128;

  f32x4 acc[4][4];
  #pragma unroll
  for (int i = 0; i < 4; i++)
    #pragma unroll
    for (int j = 0; j < 4; j++)
      acc[i][j] = (f32x4){0.f, 0.f, 0.f, 0.f};

  const int r = tid >> 3;            // 0..31
  const int ccol = (tid & 7) * 8;    // 0..56

  for (int k0 = 0; k0 < K; k0 += 64){
    if (k0) __syncthreads();
    #pragma unroll
    for (int rr = 0; rr < 4; rr++){
      int row = r + rr * 32;
      *reinterpret_cast<short8*>(&As[row][ccol]) =
        *reinterpret_cast<const short8*>(&A[(bm + row) * K + k0 + ccol]);
      *reinterpret_cast<short8*>(&Bs[row][ccol]) =
        *reinterpret_cast<const short8*>(&Bt[(bn + row) * K + k0 + ccol]);
    }
    __syncthreads();
    #pragma unroll
    for (int kk = 0; kk < 64; kk += 32){
      short8 af[4], bf[4];
      #pragma unroll
      for (int mi = 0; mi < 4; mi++)
        af[mi] = *reinterpret_cast<const short8*>(&As[wm + mi*16 + lo][kk + hi*8]);
      #pragma unroll
      for (int ni = 0; ni < 4; ni++)
        bf[ni] = *reinterpret_cast<const short8*>(&Bs[wn + ni*16 + lo][kk + hi*8]);
      #pragma unroll
      for (int mi = 0; mi < 4; mi++)
        #pragma unroll
        for (int ni = 0; ni < 4; ni++)
          acc[mi][ni] = __builtin_amdgcn_mfma_f32_16x16x32_bf16(af[mi], bf[ni], acc[mi][ni], 0, 0, 0);
    }
  }

  #pragma unroll
  for (int mi = 0; mi < 4; mi++){
    #pragma unroll
    for (int ni = 0; ni < 4; ni++){
      #pragma unroll
      for (int rg = 0; rg < 4; rg++){
        long rowg = bm + wm + mi*16 + hi*4 + rg;
        long colg = bn + wn + ni*16 + lo;
        float v = acc[mi][ni][rg] + bias[colg];
        if (MODE == 0){
          int part = (int)(colg >> 10), cc = (int)(colg & 1023);
          int h = cc >> 6, d = cc & 63;
          long b = rowg >> 11, t = rowg & 2047;
          if (part == 0) v *= 0.125f;   // fold 1/sqrt(HD) into Q (exact in bf16)
          u16* dst = (part == 0) ? Qo : ((part == 1) ? Ko : Vo);
          dst[(((b << 4) + h) * 2048 + t) * 64 + d] = f2bf(v);
        } else {
          Cf[rowg * (long)N + colg] = v;
        }
      }
    }
  }
}

// ---------------- V transpose: [bh][t][d] -> [bh][d][t] ----------------
__global__ __launch_bounds__(256)
void vtrans_kernel(const u16* __restrict__ V, u16* __restrict__ Vt){
  __shared__ u16 Ls[64][72];
  const int bh = blockIdx.y;
  const int t0 = blockIdx.x * 64;
  const u16* Vb = V + ((size_t)bh * 2048 + t0) * 64;
  u16* Ob = Vt + (size_t)bh * 64 * 2048 + t0;
  const int r = threadIdx.x >> 3;        // 0..31
  const int c = (threadIdx.x & 7) * 8;   // 0..56
  #pragma unroll
  for (int rr = 0; rr < 64; rr += 32){
    int row = r + rr;
    // XOR-swizzle 16-col groups by row's bits 4..5 -> conflict-free column reads
    *reinterpret_cast<short8*>(&Ls[row][c ^ (((row >> 4) & 3) << 4)]) =
      *reinterpret_cast<const short8*>(&Vb[(size_t)row * 64 + c]);
  }
  __syncthreads();
  const int d  = threadIdx.x >> 2;       // 0..63
  const int tc = (threadIdx.x & 3) * 16; // 0,16,32,48
  const int v  = ((tc >> 4) & 3) << 4;
  short8 o0, o1;
  #pragma unroll
  for (int j = 0; j < 8; j++) o0[j] = (short)Ls[tc + j][d ^ v];
  #pragma unroll
  for (int j = 0; j < 8; j++) o1[j] = (short)Ls[tc + 8 + j][d ^ v];
  *reinterpret_cast<short8*>(&Ob[(size_t)d * 2048 + tc]) = o0;
  *reinterpret_cast<short8*>(&Ob[(size_t)d * 2048 + tc + 8]) = o1;
}

// ---------------- causal flash attention, barrier-free waves ----------------
// Q,K: [64 bh][2048 t][64 d] bf16 (Q pre-scaled).  Vt: [64 bh][64 d][2048 t].
// Y: [B,T,C] bf16 (head-merged). One wave = 16 q rows; KV tile = 64.
__global__ __launch_bounds__(256)
void attn_kernel(const u16* __restrict__ Q, const u16* __restrict__ K,
                 const u16* __restrict__ Vt, u16* __restrict__ Y)
{
  __shared__ u16 Ps[4][2][16][72];   // per-wave, tile-parity double-buffered
  const int flat = blockIdx.x;                    // 0..2047
  const int bh = (flat & 7) * 8 + ((flat >> 3) & 7);  // XCD-chunk: 8 bh per XCD
  const int qb = flat >> 6;                       // 0..31
  const int tid = threadIdx.x, wave = tid >> 6, lane = tid & 63;
  const int lo = lane & 15, hi = lane >> 4;
  const int q0w = qb * 64 + wave * 16;
  const u16* Qb = Q  + (size_t)bh * 2048 * 64;
  const u16* Kb = K  + (size_t)bh * 2048 * 64;
  const u16* Vb = Vt + (size_t)bh * 64 * 2048;

  // Q A-fragments: row=lo, k(d)=kk*32+hi*8+j
  short8 qf0 = *reinterpret_cast<const short8*>(&Qb[(size_t)(q0w + lo) * 64 + hi * 8]);
  short8 qf1 = *reinterpret_cast<const short8*>(&Qb[(size_t)(q0w + lo) * 64 + 32 + hi * 8]);

  f32x4 o[4];
  float m[4], l[4];
  #pragma unroll
  for (int i = 0; i < 4; i++){ o[i] = (f32x4){0.f,0.f,0.f,0.f}; m[i] = -1e30f; l[i] = 0.f; }

  // full tiles: k0+63 <= q0w  ->  F = (q0w>=64) ? (q0w-64)/64 + 1 : 0
  // exactly one masked (diagonal) tile at jt==F since 16-row q-span fits one 64-kv tile
  const int F = (q0w >= 64) ? (((q0w - 64) >> 6) + 1) : 0;

  for (int jt = 0; jt <= F; jt++){
    const int k0 = jt << 6;
    // ---- S = Q K^T over 64 kv (B-frag: col=kv=lo, k(d)=hi*8+j) ----
    f32x4 s[4];
    #pragma unroll
    for (int n = 0; n < 4; n++){
      const u16* kp = &Kb[(size_t)(k0 + n * 16 + lo) * 64];
      short8 kf0 = *reinterpret_cast<const short8*>(kp + hi * 8);
      short8 kf1 = *reinterpret_cast<const short8*>(kp + 32 + hi * 8);
      f32x4 acc = (f32x4){0.f,0.f,0.f,0.f};
      acc = __builtin_amdgcn_mfma_f32_16x16x32_bf16(qf0, kf0, acc, 0, 0, 0);
      acc = __builtin_amdgcn_mfma_f32_16x16x32_bf16(qf1, kf1, acc, 0, 0, 0);
      s[n] = acc;
    }
    if (jt == F){   // diagonal tile: causal mask (C-layout: row q=hi*4+rg, col kv=n*16+lo)
      #pragma unroll
      for (int n = 0; n < 4; n++)
        #pragma unroll
        for (int rg = 0; rg < 4; rg++){
          int qq = q0w + hi * 4 + rg;
          int kv = k0 + n * 16 + lo;
          if (kv > qq) s[n][rg] = -1e30f;
        }
    }
    // ---- online softmax (reduce across the 16 lanes of each row) ----
    float alpha[4];
    #pragma unroll
    for (int rg = 0; rg < 4; rg++){
      float rm = fmaxf(fmaxf(s[0][rg], s[1][rg]), fmaxf(s[2][rg], s[3][rg]));
      rm = fmaxf(rm, __shfl_xor(rm, 1));
      rm = fmaxf(rm, __shfl_xor(rm, 2));
      rm = fmaxf(rm, __shfl_xor(rm, 4));
      rm = fmaxf(rm, __shfl_xor(rm, 8));
      float mn = fmaxf(m[rg], rm);
      float rs = 0.f;
      #pragma unroll
      for (int n = 0; n < 4; n++){
        float p = __expf(s[n][rg] - mn);
        s[n][rg] = p;
        rs += p;
      }
      rs += __shfl_xor(rs, 1);
      rs += __shfl_xor(rs, 2);
      rs += __shfl_xor(rs, 4);
      rs += __shfl_xor(rs, 8);
      alpha[rg] = __expf(m[rg] - mn);
      l[rg] = l[rg] * alpha[rg] + rs;
      m[rg] = mn;
    }
    #pragma unroll
    for (int n = 0; n < 4; n++)
      #pragma unroll
      for (int rg = 0; rg < 4; rg++)
        o[n][rg] *= alpha[rg];
    // ---- P -> per-wave LDS (re-fragment), no block barrier ----
    const int pb = jt & 1;
    #pragma unroll
    for (int n = 0; n < 4; n++)
      #pragma unroll
      for (int rg = 0; rg < 4; rg++)
        Ps[wave][pb][hi * 4 + rg][n * 16 + lo] = f2bf(s[n][rg]);
    asm volatile("s_waitcnt lgkmcnt(0)" ::: "memory");
    __builtin_amdgcn_sched_barrier(0);
    short8 pf0 = *reinterpret_cast<const short8*>(&Ps[wave][pb][lo][hi * 8]);
    short8 pf1 = *reinterpret_cast<const short8*>(&Ps[wave][pb][lo][32 + hi * 8]);
    // ---- PV: B-frag from Vt (col d = n*16+lo, k(kv)=kk*32+hi*8+j) ----
    #pragma unroll
    for (int n = 0; n < 4; n++){
      const u16* vp = &Vb[(size_t)(n * 16 + lo) * 2048 + k0];
      short8 vf0 = *reinterpret_cast<const short8*>(vp + hi * 8);
      short8 vf1 = *reinterpret_cast<const short8*>(vp + 32 + hi * 8);
      o[n] = __builtin_amdgcn_mfma_f32_16x16x32_bf16(pf0, vf0, o[n], 0, 0, 0);
      o[n] = __builtin_amdgcn_mfma_f32_16x16x32_bf16(pf1, vf1, o[n], 0, 0, 0);
    }
  }

  // epilogue: y[b][t][h*64+d]
  const int b = bh >> 4, h = bh & 15;
  #pragma unroll
  for (int rg = 0; rg < 4; rg++){
    int qq = q0w + hi * 4 + rg;
    float inv = 1.f / l[rg];
    #pragma unroll
    for (int n = 0; n < 4; n++)
      Y[((size_t)(b * 2048 + qq)) * 1024 + h * 64 + n * 16 + lo] = f2bf(o[n][rg] * inv);
  }
}

// ---------------- launch ----------------
extern "C" void kernel_launch(void* const* d_in, const int* in_sizes, int n_in,
                              void* d_out, int out_size, void* d_ws, size_t ws_size,
                              hipStream_t stream)
{
  const float* x      = (const float*)d_in[0];
  const float* w_qkv  = (const float*)d_in[1];
  const float* b_qkv  = (const float*)d_in[2];
  const float* w_proj = (const float*)d_in[3];
  const float* b_proj = (const float*)d_in[4];
  float* out = (float*)d_out;

  char* ws = (char*)d_ws;
  u16* xb     = (u16*)(ws);                       // 16 MB  [8192,1024]  (reused as vtb)
  u16* wqkvb  = (u16*)(ws + (16u << 20));         //  6 MB  [3072,1024]
  u16* wprojb = (u16*)(ws + (22u << 20));         //  2 MB  [1024,1024]
  u16* qb     = (u16*)(ws + (24u << 20));         // 16 MB  [64,2048,64]
  u16* kb     = (u16*)(ws + (40u << 20));         // 16 MB
  u16* vb     = (u16*)(ws + (56u << 20));         // 16 MB
  u16* yb     = (u16*)(ws + (72u << 20));         // 16 MB  [8192,1024]
  u16* vtb    = xb;                               // 16 MB  [64,64,2048] (after GEMM1, xb is dead)

  int nx  = B_ * T_ * C_ / 4;         // 2097152
  int nw1 = 3 * C_ * C_ / 4;          //  786432
  int nw2 = C_ * C_ / 4;              //  262144
  cvt_kernel<<<(nx  + 255) / 256, 256, 0, stream>>>(x,      xb,     nx);
  cvt_kernel<<<(nw1 + 255) / 256, 256, 0, stream>>>(w_qkv,  wqkvb,  nw1);
  cvt_kernel<<<(nw2 + 255) / 256, 256, 0, stream>>>(w_proj, wprojb, nw2);

  dim3 g1(3072 / 128, M_ / 128);
  gemm_bt<0><<<g1, 256, 0, stream>>>(xb, wqkvb, b_qkv, nullptr, qb, kb, vb, 3072, C_);

  dim3 gt(T_ / 64, B_ * H_);
  vtrans_kernel<<<gt, 256, 0, stream>>>(vb, vtb);

  attn_kernel<<<2048, 256, 0, stream>>>(qb, kb, vtb, yb);

  dim3 g2(1024 / 128, M_ / 128);
  gemm_bt<1><<<g2, 256, 0, stream>>>(yb, wprojb, b_proj, out, nullptr, nullptr, nullptr, C_, C_);
}